// Round 1
// baseline (690.199 us; speedup 1.0000x reference)
//
#include <hip/hip_runtime.h>
#include <hip/hip_bf16.h>
#include <stdint.h>

#define DDIM 1024
#define NEXP 8
#define SEG  16384   // per-expert token capacity (worst case: every token picks it)

typedef __attribute__((ext_vector_type(8))) short bf16x8;
typedef __attribute__((ext_vector_type(4))) float f32x4;
typedef __attribute__((ext_vector_type(8))) unsigned short u16x8;

__device__ __forceinline__ unsigned short f2bf(float f) {
    union { float f; unsigned int u; } v; v.f = f;
    unsigned int u = v.u;
    return (unsigned short)((u + 0x7FFFu + ((u >> 16) & 1u)) >> 16);
}

// ---------------- Kernel A: convert We fp32 -> bf16 ----------------
__global__ void cvt_we(const float* __restrict__ We, unsigned short* __restrict__ web) {
    size_t idx = ((size_t)blockIdx.x * 256 + threadIdx.x) * 8;
    const float4* p = (const float4*)(We + idx);
    float4 a = p[0], b = p[1];
    u16x8 h;
    h[0] = f2bf(a.x); h[1] = f2bf(a.y); h[2] = f2bf(a.z); h[3] = f2bf(a.w);
    h[4] = f2bf(b.x); h[5] = f2bf(b.y); h[6] = f2bf(b.z); h[7] = f2bf(b.w);
    *(u16x8*)(web + idx) = h;
}

// ---------------- Kernel B: fp32 gating + top-2 route + x fp32->bf16 ----------------
// one wave per token; lane covers 16 contiguous cols
__global__ void gate_route(const float* __restrict__ x, const float* __restrict__ Wg,
                           const float* __restrict__ bg, unsigned short* __restrict__ xb,
                           int* __restrict__ cnt, int* __restrict__ tok_list,
                           float* __restrict__ gate_list) {
    int wave = threadIdx.x >> 6, lane = threadIdx.x & 63;
    int t = blockIdx.x * 4 + wave;
    const float* xr = x + (size_t)t * DDIM;
    int c0 = lane * 16;

    float4 v[4];
#pragma unroll
    for (int j = 0; j < 4; j++) v[j] = ((const float4*)(xr + c0))[j];

    // fused bf16 conversion of x
    u16x8 h0, h1;
    h0[0] = f2bf(v[0].x); h0[1] = f2bf(v[0].y); h0[2] = f2bf(v[0].z); h0[3] = f2bf(v[0].w);
    h0[4] = f2bf(v[1].x); h0[5] = f2bf(v[1].y); h0[6] = f2bf(v[1].z); h0[7] = f2bf(v[1].w);
    h1[0] = f2bf(v[2].x); h1[1] = f2bf(v[2].y); h1[2] = f2bf(v[2].z); h1[3] = f2bf(v[2].w);
    h1[4] = f2bf(v[3].x); h1[5] = f2bf(v[3].y); h1[6] = f2bf(v[3].z); h1[7] = f2bf(v[3].w);
    u16x8* xo = (u16x8*)(xb + (size_t)t * DDIM + c0);
    xo[0] = h0; xo[1] = h1;

    // fp32 gate logits (routing fidelity vs reference)
    float acc[NEXP];
#pragma unroll
    for (int e = 0; e < NEXP; e++) {
        const float4* wg = (const float4*)(Wg + e * DDIM + c0);
        float s = 0.f;
#pragma unroll
        for (int j = 0; j < 4; j++) {
            float4 w = wg[j];
            s += v[j].x * w.x + v[j].y * w.y + v[j].z * w.z + v[j].w * w.w;
        }
        acc[e] = s;
    }
#pragma unroll
    for (int e = 0; e < NEXP; e++) {
#pragma unroll
        for (int o = 32; o > 0; o >>= 1) acc[e] += __shfl_xor(acc[e], o, 64);
    }

    if (lane == 0) {
        float l1 = -1e30f, l2 = -1e30f; int e1 = 0, e2 = 0;
#pragma unroll
        for (int e = 0; e < NEXP; e++) {
            float le = acc[e] + bg[e];
            if (le > l1) { l2 = l1; e2 = e1; l1 = le; e1 = e; }
            else if (le > l2) { l2 = le; e2 = e; }
        }
        float g1 = 1.0f / (1.0f + expf(l2 - l1));
        float g2 = 1.0f - g1;
        int p1 = atomicAdd(cnt + e1, 1);
        tok_list[e1 * SEG + p1] = t; gate_list[e1 * SEG + p1] = g1;
        int p2 = atomicAdd(cnt + e2, 1);
        tok_list[e2 * SEG + p2] = t; gate_list[e2 * SEG + p2] = g2;
    }
}

// ---------------- Kernel C: per-expert gathered GEMM, bf16 MFMA ----------------
// C[row, col] = sum_d xb[token[row], d] * web[e, col, d]  (NT layout)
// 128x128 tile, BK=64, 4 waves in 2x2, 16x16x32 MFMA, XOR-swizzled LDS granules.
__global__ __launch_bounds__(256, 3) void moe_gemm(
    const unsigned short* __restrict__ xb, const unsigned short* __restrict__ web,
    const float* __restrict__ be, const int* __restrict__ cnt,
    const int* __restrict__ tok_list, const float* __restrict__ gate_list,
    float* __restrict__ out) {

    int e = blockIdx.y >> 7;
    int m0 = (blockIdx.y & 127) << 7;
    int c = cnt[e];
    if (m0 >= c) return;
    int n0 = blockIdx.x << 7;

    __shared__ unsigned short lA[128 * 64];   // 16 KB
    __shared__ unsigned short lB[128 * 64];   // 16 KB
    __shared__ int   tok_s[128];
    __shared__ float gate_s[128];

    int tid = threadIdx.x;
    int wave = tid >> 6, lane = tid & 63;

    if (tid < 128) {
        int r = m0 + tid;
        int rc = min(r, c - 1);
        tok_s[tid]  = tok_list[e * SEG + rc];
        gate_s[tid] = (r < c) ? gate_list[e * SEG + rc] : 0.0f;
    }
    __syncthreads();

    // staging: issue t=wave*4+j covers tile rows 8t..8t+7; lane -> (row 8t+lane/8, dst granule lane%8)
    // LDS[row][gd] holds source granule gd ^ (row&7)   (granule = 16B = 8 bf16)
    int rsub = lane >> 3;
    int gsrc = (lane & 7) ^ rsub;

    const unsigned short* agp[4];
    const unsigned short* bgp[4];
#pragma unroll
    for (int j = 0; j < 4; j++) {
        int row = (wave * 4 + j) * 8 + rsub;
        agp[j] = xb + (size_t)tok_s[row] * DDIM + gsrc * 8;
        bgp[j] = web + ((size_t)e << 20) + (size_t)(n0 + row) * DDIM + gsrc * 8;
    }

    f32x4 acc[4][4];
    f32x4 zz = {0.f, 0.f, 0.f, 0.f};
#pragma unroll
    for (int mi = 0; mi < 4; mi++)
#pragma unroll
        for (int ni = 0; ni < 4; ni++) acc[mi][ni] = zz;

    int wm = (wave >> 1) * 64;
    int wn = (wave & 1) * 64;
    int mrow = lane & 15;
    int q = lane >> 4;

    int offA[4], swA[4], offB[4], swB[4];
#pragma unroll
    for (int i = 0; i < 4; i++) {
        int ra = wm + i * 16 + mrow;
        offA[i] = ra * 64; swA[i] = ra & 7;
        int rb = wn + i * 16 + mrow;
        offB[i] = rb * 64; swB[i] = rb & 7;
    }

    for (int kt = 0; kt < 16; kt++) {
        int k0 = kt * 64;
#pragma unroll
        for (int j = 0; j < 4; j++) {
            __builtin_amdgcn_global_load_lds(
                (const __attribute__((address_space(1))) void*)(agp[j] + k0),
                (__attribute__((address_space(3))) void*)(&lA[(wave * 4 + j) * 512]),
                16, 0, 0);
            __builtin_amdgcn_global_load_lds(
                (const __attribute__((address_space(1))) void*)(bgp[j] + k0),
                (__attribute__((address_space(3))) void*)(&lB[(wave * 4 + j) * 512]),
                16, 0, 0);
        }
        __syncthreads();
#pragma unroll
        for (int kh = 0; kh < 2; kh++) {
            int gq = kh * 4 + q;
            bf16x8 af[4], bfr[4];
#pragma unroll
            for (int i = 0; i < 4; i++)
                af[i] = *(const bf16x8*)&lA[offA[i] + ((gq ^ swA[i]) << 3)];
#pragma unroll
            for (int i = 0; i < 4; i++)
                bfr[i] = *(const bf16x8*)&lB[offB[i] + ((gq ^ swB[i]) << 3)];
#pragma unroll
            for (int mi = 0; mi < 4; mi++)
#pragma unroll
                for (int ni = 0; ni < 4; ni++)
                    acc[mi][ni] = __builtin_amdgcn_mfma_f32_16x16x32_bf16(
                        af[mi], bfr[ni], acc[mi][ni], 0, 0, 0);
        }
        __syncthreads();
    }

    // epilogue: D[row=(lane>>4)*4+r][col=lane&15] per 16x16 frag; scatter-add with gate
#pragma unroll
    for (int ni = 0; ni < 4; ni++) {
        int col = n0 + wn + ni * 16 + mrow;
        float bias = be[e * DDIM + col];
#pragma unroll
        for (int mi = 0; mi < 4; mi++) {
#pragma unroll
            for (int r = 0; r < 4; r++) {
                int rl = wm + mi * 16 + q * 4 + r;
                if (m0 + rl < c) {
                    float g = gate_s[rl];
                    atomicAdd(out + (size_t)tok_s[rl] * DDIM + col,
                              g * (acc[mi][ni][r] + bias));
                }
            }
        }
    }
}

extern "C" void kernel_launch(void* const* d_in, const int* in_sizes, int n_in,
                              void* d_out, int out_size, void* d_ws, size_t ws_size,
                              hipStream_t stream) {
    const float* x  = (const float*)d_in[0];
    const float* Wg = (const float*)d_in[1];
    const float* bg = (const float*)d_in[2];
    const float* We = (const float*)d_in[3];
    const float* be = (const float*)d_in[4];
    float* out = (float*)d_out;

    char* ws = (char*)d_ws;
    unsigned short* xb  = (unsigned short*)ws;                          // 32 MB
    unsigned short* web = (unsigned short*)(ws + (33554432));           // 16 MB
    int*   tok_list  = (int*)(ws + 33554432 + 16777216);                // 512 KB
    float* gate_list = (float*)(ws + 33554432 + 16777216 + 524288);     // 512 KB
    int*   cnt       = (int*)(ws + 33554432 + 16777216 + 1048576);      // 32 B

    hipMemsetAsync(cnt, 0, NEXP * sizeof(int), stream);
    hipMemsetAsync(d_out, 0, (size_t)out_size * sizeof(float), stream);

    cvt_we<<<4096, 256, 0, stream>>>(We, web);
    gate_route<<<4096, 256, 0, stream>>>(x, Wg, bg, xb, cnt, tok_list, gate_list);
    moe_gemm<<<dim3(8, 1024), 256, 0, stream>>>(xb, web, be, cnt, tok_list, gate_list, out);
}

// Round 2
// 375.548 us; speedup vs baseline: 1.8378x; 1.8378x over previous
//
#include <hip/hip_runtime.h>
#include <hip/hip_bf16.h>
#include <stdint.h>

#define DDIM 1024
#define NEXP 8
#define SEG  16384   // per-expert token capacity (worst case: every token picks it)

typedef __attribute__((ext_vector_type(8))) short bf16x8;
typedef __attribute__((ext_vector_type(4))) float f32x4;
typedef __attribute__((ext_vector_type(8))) unsigned short u16x8;

__device__ __forceinline__ unsigned short f2bf(float f) {
    union { float f; unsigned int u; } v; v.f = f;
    unsigned int u = v.u;
    return (unsigned short)((u + 0x7FFFu + ((u >> 16) & 1u)) >> 16);
}

// ---------------- Kernel A: convert We fp32 -> bf16 ----------------
__global__ void cvt_we(const float* __restrict__ We, unsigned short* __restrict__ web) {
    size_t idx = ((size_t)blockIdx.x * 256 + threadIdx.x) * 8;
    const float4* p = (const float4*)(We + idx);
    float4 a = p[0], b = p[1];
    u16x8 h;
    h[0] = f2bf(a.x); h[1] = f2bf(a.y); h[2] = f2bf(a.z); h[3] = f2bf(a.w);
    h[4] = f2bf(b.x); h[5] = f2bf(b.y); h[6] = f2bf(b.z); h[7] = f2bf(b.w);
    *(u16x8*)(web + idx) = h;
}

// ---------------- Kernel B: fp32 gating + top-2 route + x fp32->bf16 ----------------
// 512 threads = 8 waves per block; each wave handles 4 tokens (32 tokens/block).
// Routing decisions aggregated in LDS; ONE atomicAdd per (block, expert) to
// reserve a segment range -> 32768 same-address atomics become <=4096.
__global__ __launch_bounds__(512) void gate_route(
    const float* __restrict__ x, const float* __restrict__ Wg,
    const float* __restrict__ bg, unsigned short* __restrict__ xb,
    int* __restrict__ cnt, int* __restrict__ tok_list,
    float* __restrict__ gate_list) {

    int wave = threadIdx.x >> 6, lane = threadIdx.x & 63;
    int tbase = blockIdx.x * 32;

    __shared__ int   se[64];   // entry = local_token*2 + slot
    __shared__ float sg[64];

#pragma unroll
    for (int i = 0; i < 4; i++) {
        int lt = wave * 4 + i;
        int t = tbase + lt;
        const float* xr = x + (size_t)t * DDIM;
        int c0 = lane * 16;

        float4 v[4];
#pragma unroll
        for (int j = 0; j < 4; j++) v[j] = ((const float4*)(xr + c0))[j];

        // fused bf16 conversion of x
        u16x8 h0, h1;
        h0[0] = f2bf(v[0].x); h0[1] = f2bf(v[0].y); h0[2] = f2bf(v[0].z); h0[3] = f2bf(v[0].w);
        h0[4] = f2bf(v[1].x); h0[5] = f2bf(v[1].y); h0[6] = f2bf(v[1].z); h0[7] = f2bf(v[1].w);
        h1[0] = f2bf(v[2].x); h1[1] = f2bf(v[2].y); h1[2] = f2bf(v[2].z); h1[3] = f2bf(v[2].w);
        h1[4] = f2bf(v[3].x); h1[5] = f2bf(v[3].y); h1[6] = f2bf(v[3].z); h1[7] = f2bf(v[3].w);
        u16x8* xo = (u16x8*)(xb + (size_t)t * DDIM + c0);
        xo[0] = h0; xo[1] = h1;

        // fp32 gate logits (routing fidelity vs reference)
        float acc[NEXP];
#pragma unroll
        for (int e = 0; e < NEXP; e++) {
            const float4* wg = (const float4*)(Wg + e * DDIM + c0);
            float s = 0.f;
#pragma unroll
            for (int j = 0; j < 4; j++) {
                float4 w = wg[j];
                s += v[j].x * w.x + v[j].y * w.y + v[j].z * w.z + v[j].w * w.w;
            }
            acc[e] = s;
        }
#pragma unroll
        for (int e = 0; e < NEXP; e++) {
#pragma unroll
            for (int o = 32; o > 0; o >>= 1) acc[e] += __shfl_xor(acc[e], o, 64);
        }

        if (lane == 0) {
            float l1 = -1e30f, l2 = -1e30f; int e1 = 0, e2 = 0;
#pragma unroll
            for (int e = 0; e < NEXP; e++) {
                float le = acc[e] + bg[e];
                if (le > l1) { l2 = l1; e2 = e1; l1 = le; e1 = e; }
                else if (le > l2) { l2 = le; e2 = e; }
            }
            float g1 = 1.0f / (1.0f + __expf(l2 - l1));
            float g2 = 1.0f - g1;
            se[lt * 2]     = e1; sg[lt * 2]     = g1;
            se[lt * 2 + 1] = e2; sg[lt * 2 + 1] = g2;
        }
    }
    __syncthreads();

    // one thread per expert: count, reserve range with ONE atomic, scatter.
    if (threadIdx.x < NEXP) {
        int e = threadIdx.x;
        int k = 0;
#pragma unroll 8
        for (int i = 0; i < 64; i++) k += (se[i] == e);
        if (k) {
            int p = atomicAdd(cnt + e, k);
            for (int i = 0; i < 64; i++) {
                if (se[i] == e) {
                    tok_list[e * SEG + p]  = tbase + (i >> 1);
                    gate_list[e * SEG + p] = sg[i];
                    p++;
                }
            }
        }
    }
}

// ---------------- Kernel C: per-expert gathered GEMM, bf16 MFMA ----------------
// C[row, col] = sum_d xb[token[row], d] * web[e, col, d]  (NT layout)
// 128x128 tile, BK=64, 4 waves in 2x2, 16x16x32 MFMA, XOR-swizzled LDS granules.
__global__ __launch_bounds__(256, 3) void moe_gemm(
    const unsigned short* __restrict__ xb, const unsigned short* __restrict__ web,
    const float* __restrict__ be, const int* __restrict__ cnt,
    const int* __restrict__ tok_list, const float* __restrict__ gate_list,
    float* __restrict__ out) {

    int e = blockIdx.y >> 7;
    int m0 = (blockIdx.y & 127) << 7;
    int c = cnt[e];
    if (m0 >= c) return;
    int n0 = blockIdx.x << 7;

    __shared__ unsigned short lA[128 * 64];   // 16 KB
    __shared__ unsigned short lB[128 * 64];   // 16 KB
    __shared__ int   tok_s[128];
    __shared__ float gate_s[128];

    int tid = threadIdx.x;
    int wave = tid >> 6, lane = tid & 63;

    if (tid < 128) {
        int r = m0 + tid;
        int rc = min(r, c - 1);
        tok_s[tid]  = tok_list[e * SEG + rc];
        gate_s[tid] = (r < c) ? gate_list[e * SEG + rc] : 0.0f;
    }
    __syncthreads();

    // staging: issue t=wave*4+j covers tile rows 8t..8t+7; lane -> (row 8t+lane/8, dst granule lane%8)
    // LDS[row][gd] holds source granule gd ^ (row&7)   (granule = 16B = 8 bf16)
    int rsub = lane >> 3;
    int gsrc = (lane & 7) ^ rsub;

    const unsigned short* agp[4];
    const unsigned short* bgp[4];
#pragma unroll
    for (int j = 0; j < 4; j++) {
        int row = (wave * 4 + j) * 8 + rsub;
        agp[j] = xb + (size_t)tok_s[row] * DDIM + gsrc * 8;
        bgp[j] = web + ((size_t)e << 20) + (size_t)(n0 + row) * DDIM + gsrc * 8;
    }

    f32x4 acc[4][4];
    f32x4 zz = {0.f, 0.f, 0.f, 0.f};
#pragma unroll
    for (int mi = 0; mi < 4; mi++)
#pragma unroll
        for (int ni = 0; ni < 4; ni++) acc[mi][ni] = zz;

    int wm = (wave >> 1) * 64;
    int wn = (wave & 1) * 64;
    int mrow = lane & 15;
    int q = lane >> 4;

    int offA[4], swA[4], offB[4], swB[4];
#pragma unroll
    for (int i = 0; i < 4; i++) {
        int ra = wm + i * 16 + mrow;
        offA[i] = ra * 64; swA[i] = ra & 7;
        int rb = wn + i * 16 + mrow;
        offB[i] = rb * 64; swB[i] = rb & 7;
    }

    for (int kt = 0; kt < 16; kt++) {
        int k0 = kt * 64;
#pragma unroll
        for (int j = 0; j < 4; j++) {
            __builtin_amdgcn_global_load_lds(
                (const __attribute__((address_space(1))) void*)(agp[j] + k0),
                (__attribute__((address_space(3))) void*)(&lA[(wave * 4 + j) * 512]),
                16, 0, 0);
            __builtin_amdgcn_global_load_lds(
                (const __attribute__((address_space(1))) void*)(bgp[j] + k0),
                (__attribute__((address_space(3))) void*)(&lB[(wave * 4 + j) * 512]),
                16, 0, 0);
        }
        __syncthreads();
#pragma unroll
        for (int kh = 0; kh < 2; kh++) {
            int gq = kh * 4 + q;
            bf16x8 af[4], bfr[4];
#pragma unroll
            for (int i = 0; i < 4; i++)
                af[i] = *(const bf16x8*)&lA[offA[i] + ((gq ^ swA[i]) << 3)];
#pragma unroll
            for (int i = 0; i < 4; i++)
                bfr[i] = *(const bf16x8*)&lB[offB[i] + ((gq ^ swB[i]) << 3)];
#pragma unroll
            for (int mi = 0; mi < 4; mi++)
#pragma unroll
                for (int ni = 0; ni < 4; ni++)
                    acc[mi][ni] = __builtin_amdgcn_mfma_f32_16x16x32_bf16(
                        af[mi], bfr[ni], acc[mi][ni], 0, 0, 0);
        }
        __syncthreads();
    }

    // epilogue: D[row=(lane>>4)*4+r][col=lane&15] per 16x16 frag; scatter-add with gate
#pragma unroll
    for (int ni = 0; ni < 4; ni++) {
        int col = n0 + wn + ni * 16 + mrow;
        float bias = be[e * DDIM + col];
#pragma unroll
        for (int mi = 0; mi < 4; mi++) {
#pragma unroll
            for (int r = 0; r < 4; r++) {
                int rl = wm + mi * 16 + q * 4 + r;
                if (m0 + rl < c) {
                    float g = gate_s[rl];
                    atomicAdd(out + (size_t)tok_s[rl] * DDIM + col,
                              g * (acc[mi][ni][r] + bias));
                }
            }
        }
    }
}

extern "C" void kernel_launch(void* const* d_in, const int* in_sizes, int n_in,
                              void* d_out, int out_size, void* d_ws, size_t ws_size,
                              hipStream_t stream) {
    const float* x  = (const float*)d_in[0];
    const float* Wg = (const float*)d_in[1];
    const float* bg = (const float*)d_in[2];
    const float* We = (const float*)d_in[3];
    const float* be = (const float*)d_in[4];
    float* out = (float*)d_out;

    char* ws = (char*)d_ws;
    unsigned short* xb  = (unsigned short*)ws;                          // 32 MB
    unsigned short* web = (unsigned short*)(ws + (33554432));           // 16 MB
    int*   tok_list  = (int*)(ws + 33554432 + 16777216);                // 512 KB
    float* gate_list = (float*)(ws + 33554432 + 16777216 + 524288);     // 512 KB
    int*   cnt       = (int*)(ws + 33554432 + 16777216 + 1048576);      // 32 B

    hipMemsetAsync(cnt, 0, NEXP * sizeof(int), stream);
    hipMemsetAsync(d_out, 0, (size_t)out_size * sizeof(float), stream);

    cvt_we<<<4096, 256, 0, stream>>>(We, web);
    gate_route<<<512, 512, 0, stream>>>(x, Wg, bg, xb, cnt, tok_list, gate_list);
    moe_gemm<<<dim3(8, 1024), 256, 0, stream>>>(xb, web, be, cnt, tok_list, gate_list, out);
}

// Round 3
// 336.586 us; speedup vs baseline: 2.0506x; 1.1158x over previous
//
#include <hip/hip_runtime.h>
#include <hip/hip_bf16.h>
#include <stdint.h>

#define DDIM 1024
#define NEXP 8
#define SEG  16384   // per-expert token capacity (worst case: every token picks it)

typedef __attribute__((ext_vector_type(8))) short bf16x8;
typedef __attribute__((ext_vector_type(4))) float f32x4;
typedef __attribute__((ext_vector_type(8))) unsigned short u16x8;

__device__ __forceinline__ unsigned short f2bf(float f) {
    union { float f; unsigned int u; } v; v.f = f;
    unsigned int u = v.u;
    return (unsigned short)((u + 0x7FFFu + ((u >> 16) & 1u)) >> 16);
}

// ---------------- Kernel A: convert We fp32 -> bf16 ----------------
__global__ void cvt_we(const float* __restrict__ We, unsigned short* __restrict__ web) {
    size_t idx = ((size_t)blockIdx.x * 256 + threadIdx.x) * 8;
    const float4* p = (const float4*)(We + idx);
    float4 a = p[0], b = p[1];
    u16x8 h;
    h[0] = f2bf(a.x); h[1] = f2bf(a.y); h[2] = f2bf(a.z); h[3] = f2bf(a.w);
    h[4] = f2bf(b.x); h[5] = f2bf(b.y); h[6] = f2bf(b.z); h[7] = f2bf(b.w);
    *(u16x8*)(web + idx) = h;
}

// ---------------- Kernel B: fp32 gating + top-2 route + x fp32->bf16 ----------------
// 512 threads = 8 waves per block; each wave handles 4 tokens (32 tokens/block).
// Routing decisions aggregated in LDS; ONE atomicAdd per (block, expert).
// tok_list entries are t*2+slot so the GEMM can store into a (token,slot)-
// indexed scratch without any inverse map.
__global__ __launch_bounds__(512) void gate_route(
    const float* __restrict__ x, const float* __restrict__ Wg,
    const float* __restrict__ bg, unsigned short* __restrict__ xb,
    int* __restrict__ cnt, int* __restrict__ tok_list,
    float* __restrict__ gate_list) {

    int wave = threadIdx.x >> 6, lane = threadIdx.x & 63;
    int tbase = blockIdx.x * 32;

    __shared__ int   se[64];   // entry = local_token*2 + slot
    __shared__ float sg[64];

#pragma unroll
    for (int i = 0; i < 4; i++) {
        int lt = wave * 4 + i;
        int t = tbase + lt;
        const float* xr = x + (size_t)t * DDIM;
        int c0 = lane * 16;

        float4 v[4];
#pragma unroll
        for (int j = 0; j < 4; j++) v[j] = ((const float4*)(xr + c0))[j];

        // fused bf16 conversion of x
        u16x8 h0, h1;
        h0[0] = f2bf(v[0].x); h0[1] = f2bf(v[0].y); h0[2] = f2bf(v[0].z); h0[3] = f2bf(v[0].w);
        h0[4] = f2bf(v[1].x); h0[5] = f2bf(v[1].y); h0[6] = f2bf(v[1].z); h0[7] = f2bf(v[1].w);
        h1[0] = f2bf(v[2].x); h1[1] = f2bf(v[2].y); h1[2] = f2bf(v[2].z); h1[3] = f2bf(v[2].w);
        h1[4] = f2bf(v[3].x); h1[5] = f2bf(v[3].y); h1[6] = f2bf(v[3].z); h1[7] = f2bf(v[3].w);
        u16x8* xo = (u16x8*)(xb + (size_t)t * DDIM + c0);
        xo[0] = h0; xo[1] = h1;

        // fp32 gate logits (routing fidelity vs reference)
        float acc[NEXP];
#pragma unroll
        for (int e = 0; e < NEXP; e++) {
            const float4* wg = (const float4*)(Wg + e * DDIM + c0);
            float s = 0.f;
#pragma unroll
            for (int j = 0; j < 4; j++) {
                float4 w = wg[j];
                s += v[j].x * w.x + v[j].y * w.y + v[j].z * w.z + v[j].w * w.w;
            }
            acc[e] = s;
        }
#pragma unroll
        for (int e = 0; e < NEXP; e++) {
#pragma unroll
            for (int o = 32; o > 0; o >>= 1) acc[e] += __shfl_xor(acc[e], o, 64);
        }

        if (lane == 0) {
            float l1 = -1e30f, l2 = -1e30f; int e1 = 0, e2 = 0;
#pragma unroll
            for (int e = 0; e < NEXP; e++) {
                float le = acc[e] + bg[e];
                if (le > l1) { l2 = l1; e2 = e1; l1 = le; e1 = e; }
                else if (le > l2) { l2 = le; e2 = e; }
            }
            float g1 = 1.0f / (1.0f + __expf(l2 - l1));
            float g2 = 1.0f - g1;
            se[lt * 2]     = e1; sg[lt * 2]     = g1;
            se[lt * 2 + 1] = e2; sg[lt * 2 + 1] = g2;
        }
    }
    __syncthreads();

    // one thread per expert: count, reserve range with ONE atomic, scatter.
    if (threadIdx.x < NEXP) {
        int e = threadIdx.x;
        int k = 0;
#pragma unroll 8
        for (int i = 0; i < 64; i++) k += (se[i] == e);
        if (k) {
            int p = atomicAdd(cnt + e, k);
            for (int i = 0; i < 64; i++) {
                if (se[i] == e) {
                    // entry encodes token*2 + slot (slot = i&1)
                    tok_list[e * SEG + p]  = (tbase + (i >> 1)) * 2 + (i & 1);
                    gate_list[e * SEG + p] = sg[i];
                    p++;
                }
            }
        }
    }
}

// ---------------- Kernel C: per-expert gathered GEMM, bf16 MFMA ----------------
// C[row, col] = sum_d xb[token[row], d] * web[e, col, d]  (NT layout)
// 128x128 tile, BK=64, 4 waves in 2x2, 16x16x32 MFMA, XOR-swizzled LDS granules.
// STORE mode: plain stores of g*(acc+bias) into S[token*2+slot][col] (no RMW).
// Atomic mode (fallback if ws too small): atomicAdd into out as before.
template<bool STORE>
__global__ __launch_bounds__(256, 3) void moe_gemm(
    const unsigned short* __restrict__ xb, const unsigned short* __restrict__ web,
    const float* __restrict__ be, const int* __restrict__ cnt,
    const int* __restrict__ tok_list, const float* __restrict__ gate_list,
    float* __restrict__ dst) {

    int e = blockIdx.y >> 7;
    int m0 = (blockIdx.y & 127) << 7;
    int c = cnt[e];
    if (m0 >= c) return;
    int n0 = blockIdx.x << 7;

    __shared__ unsigned short lA[128 * 64];   // 16 KB
    __shared__ unsigned short lB[128 * 64];   // 16 KB
    __shared__ int   tok_s[128];
    __shared__ float gate_s[128];

    int tid = threadIdx.x;
    int wave = tid >> 6, lane = tid & 63;

    if (tid < 128) {
        int r = m0 + tid;
        int rc = min(r, c - 1);
        tok_s[tid]  = tok_list[e * SEG + rc];
        gate_s[tid] = (r < c) ? gate_list[e * SEG + rc] : 0.0f;
    }
    __syncthreads();

    // staging: issue t=wave*4+j covers tile rows 8t..8t+7; lane -> (row 8t+lane/8, dst granule lane%8)
    // LDS[row][gd] holds source granule gd ^ (row&7)   (granule = 16B = 8 bf16)
    int rsub = lane >> 3;
    int gsrc = (lane & 7) ^ rsub;

    const unsigned short* agp[4];
    const unsigned short* bgp[4];
#pragma unroll
    for (int j = 0; j < 4; j++) {
        int row = (wave * 4 + j) * 8 + rsub;
        agp[j] = xb + (size_t)(tok_s[row] >> 1) * DDIM + gsrc * 8;
        bgp[j] = web + ((size_t)e << 20) + (size_t)(n0 + row) * DDIM + gsrc * 8;
    }

    f32x4 acc[4][4];
    f32x4 zz = {0.f, 0.f, 0.f, 0.f};
#pragma unroll
    for (int mi = 0; mi < 4; mi++)
#pragma unroll
        for (int ni = 0; ni < 4; ni++) acc[mi][ni] = zz;

    int wm = (wave >> 1) * 64;
    int wn = (wave & 1) * 64;
    int mrow = lane & 15;
    int q = lane >> 4;

    int offA[4], swA[4], offB[4], swB[4];
#pragma unroll
    for (int i = 0; i < 4; i++) {
        int ra = wm + i * 16 + mrow;
        offA[i] = ra * 64; swA[i] = ra & 7;
        int rb = wn + i * 16 + mrow;
        offB[i] = rb * 64; swB[i] = rb & 7;
    }

    for (int kt = 0; kt < 16; kt++) {
        int k0 = kt * 64;
#pragma unroll
        for (int j = 0; j < 4; j++) {
            __builtin_amdgcn_global_load_lds(
                (const __attribute__((address_space(1))) void*)(agp[j] + k0),
                (__attribute__((address_space(3))) void*)(&lA[(wave * 4 + j) * 512]),
                16, 0, 0);
            __builtin_amdgcn_global_load_lds(
                (const __attribute__((address_space(1))) void*)(bgp[j] + k0),
                (__attribute__((address_space(3))) void*)(&lB[(wave * 4 + j) * 512]),
                16, 0, 0);
        }
        __syncthreads();
#pragma unroll
        for (int kh = 0; kh < 2; kh++) {
            int gq = kh * 4 + q;
            bf16x8 af[4], bfr[4];
#pragma unroll
            for (int i = 0; i < 4; i++)
                af[i] = *(const bf16x8*)&lA[offA[i] + ((gq ^ swA[i]) << 3)];
#pragma unroll
            for (int i = 0; i < 4; i++)
                bfr[i] = *(const bf16x8*)&lB[offB[i] + ((gq ^ swB[i]) << 3)];
#pragma unroll
            for (int mi = 0; mi < 4; mi++)
#pragma unroll
                for (int ni = 0; ni < 4; ni++)
                    acc[mi][ni] = __builtin_amdgcn_mfma_f32_16x16x32_bf16(
                        af[mi], bfr[ni], acc[mi][ni], 0, 0, 0);
        }
        __syncthreads();
    }

    // epilogue: D[row=(lane>>4)*4+r][col=lane&15] per 16x16 frag
#pragma unroll
    for (int ni = 0; ni < 4; ni++) {
        int col = n0 + wn + ni * 16 + mrow;
        float bias = be[e * DDIM + col];
#pragma unroll
        for (int mi = 0; mi < 4; mi++) {
#pragma unroll
            for (int r = 0; r < 4; r++) {
                int rl = wm + mi * 16 + q * 4 + r;
                if (m0 + rl < c) {
                    float g = gate_s[rl];
                    float vv = g * (acc[mi][ni][r] + bias);
                    if (STORE) {
                        // scratch row = token*2+slot: plain store, no RMW
                        dst[(size_t)tok_s[rl] * DDIM + col] = vv;
                    } else {
                        atomicAdd(dst + (size_t)(tok_s[rl] >> 1) * DDIM + col, vv);
                    }
                }
            }
        }
    }
}

// ---------------- Kernel D: combine the two slot rows per token ----------------
// out[t] = S[2t] + S[2t+1]; float4 grid-stride, fully coalesced.
__global__ void combine(const float* __restrict__ S, float* __restrict__ out) {
    size_t i = (size_t)blockIdx.x * 256 + threadIdx.x;   // float4 index
    size_t t  = i >> 8;                                   // 256 float4 per row
    size_t c4 = i & 255;
    const float4* r0 = (const float4*)(S + t * 2 * DDIM) + c4;
    const float4* r1 = (const float4*)(S + (t * 2 + 1) * DDIM) + c4;
    float4 a = *r0, b = *r1;
    float4 o = {a.x + b.x, a.y + b.y, a.z + b.z, a.w + b.w};
    ((float4*)out)[i] = o;
}

extern "C" void kernel_launch(void* const* d_in, const int* in_sizes, int n_in,
                              void* d_out, int out_size, void* d_ws, size_t ws_size,
                              hipStream_t stream) {
    const float* x  = (const float*)d_in[0];
    const float* Wg = (const float*)d_in[1];
    const float* bg = (const float*)d_in[2];
    const float* We = (const float*)d_in[3];
    const float* be = (const float*)d_in[4];
    float* out = (float*)d_out;

    char* ws = (char*)d_ws;
    unsigned short* xb  = (unsigned short*)ws;                          // 32 MB
    unsigned short* web = (unsigned short*)(ws + 33554432);             // 16 MB
    int*   tok_list  = (int*)(ws + 33554432 + 16777216);                // 512 KB
    float* gate_list = (float*)(ws + 33554432 + 16777216 + 524288);     // 512 KB
    int*   cnt       = (int*)(ws + 33554432 + 16777216 + 1048576);      // 32 B
    float* S         = (float*)(ws + 52428800);                         // 134.2 MB (store path)

    const size_t NEED = 52428800ull + (size_t)32768 * DDIM * 4;         // ~178.7 MB

    hipMemsetAsync(cnt, 0, NEXP * sizeof(int), stream);

    cvt_we<<<4096, 256, 0, stream>>>(We, web);
    gate_route<<<512, 512, 0, stream>>>(x, Wg, bg, xb, cnt, tok_list, gate_list);

    if (ws_size >= NEED) {
        moe_gemm<true><<<dim3(8, 1024), 256, 0, stream>>>(xb, web, be, cnt, tok_list, gate_list, S);
        combine<<<16384, 256, 0, stream>>>(S, out);
    } else {
        hipMemsetAsync(d_out, 0, (size_t)out_size * sizeof(float), stream);
        moe_gemm<false><<<dim3(8, 1024), 256, 0, stream>>>(xb, web, be, cnt, tok_list, gate_list, out);
    }
}